// Round 3
// baseline (831.633 us; speedup 1.0000x reference)
//
#include <hip/hip_runtime.h>
#include <hip/hip_bf16.h>

// Qwen3VLMoeTextExpertsTransposed: E=32,H=2048,I=768,K=4,T=2048
#define E_ 32
#define H_ 2048
#define I_ 768
#define T_ 2048
#define TWO_I 1536
#define MAX_TILES 96   // sum ceil(cnt/128) <= 32 + 8192/128 = 96

typedef __attribute__((ext_vector_type(8))) short short8;
typedef __attribute__((ext_vector_type(4))) float floatx4;

// ws layout (bytes)
#define WS_OFFSETS 0                       // int[33]
#define WS_IDS     1024                    // int[8192]
#define WS_WTS     (1024 + 32768)          // float[8192]
#define WS_TILES   (1024 + 65536)          // int[96]: (e<<16)|mtile, -1 = dead
#define WS_SLOTTJ  69632                   // int[8192]: slot of (t,j) or -1
#define WS_INTER   131072                  // bf16[8192*768]
#define WS_HID16   (131072 + 8192*768*2)   // bf16[2048*2048]
#define WS_EO      21102592ULL             // fp32[8192*2048] weighted expert outs (67 MB)

__device__ __forceinline__ unsigned short f2bf(float f) {
  union { float f; unsigned u; } v; v.f = f;
  unsigned r = v.u + 0x7FFFu + ((v.u >> 16) & 1u);   // RNE
  return (unsigned short)(r >> 16);
}

__device__ __forceinline__ unsigned pkbf(float a, float b) {
  // packed fp32->bf16 RNE pair; lowers to v_cvt_pk_bf16_f32 when available
  __hip_bfloat162 h = __float22bfloat162_rn(float2{a, b});
  union { __hip_bfloat162 h; unsigned u; } v; v.h = h; return v.u;
}

// async global->LDS, 16B per lane; LDS dest = wave-uniform base + lane*16
__device__ __forceinline__ void gload_lds16(const unsigned short* g, unsigned short* l) {
  __builtin_amdgcn_global_load_lds(
      (__attribute__((address_space(1))) void*)g,
      (__attribute__((address_space(3))) void*)l, 16, 0, 0);
}

// ---- routing: group slots by expert (dedupe = numpy last-write-wins) + tile list ----
__global__ void build_routing(const int* __restrict__ idx, const float* __restrict__ w,
                              char* __restrict__ ws) {
  int* offs = (int*)(ws + WS_OFFSETS);
  int* ids  = (int*)(ws + WS_IDS);
  float* wt = (float*)(ws + WS_WTS);
  int* tiles = (int*)(ws + WS_TILES);
  int* slot_tj = (int*)(ws + WS_SLOTTJ);
  __shared__ int s_cnt[E_];
  __shared__ int s_pos[E_];
  int tid = threadIdx.x;
  if (tid < E_) s_cnt[tid] = 0;
  __syncthreads();
  for (int i = tid; i < T_ * 4; i += 256) {
    int t = i >> 2, j = i & 3;
    int e = idx[i];
    bool keep = true;
    for (int j2 = j + 1; j2 < 4; ++j2) if (idx[t * 4 + j2] == e) keep = false;
    if (keep) atomicAdd(&s_cnt[e], 1);
  }
  __syncthreads();
  if (tid == 0) {
    int run = 0;
    for (int e = 0; e < E_; ++e) { offs[e] = run; s_pos[e] = run; run += s_cnt[e]; }
    offs[E_] = run;
    int nt = 0;
    for (int e = 0; e < E_; ++e)
      for (int m0 = 0; m0 < s_cnt[e]; m0 += 128) tiles[nt++] = (e << 16) | (m0 >> 7);
    for (; nt < MAX_TILES; ++nt) tiles[nt] = -1;
  }
  __syncthreads();
  for (int i = tid; i < T_ * 4; i += 256) {
    int t = i >> 2, j = i & 3;
    int e = idx[i];
    bool keep = true;
    for (int j2 = j + 1; j2 < 4; ++j2) if (idx[t * 4 + j2] == e) keep = false;
    if (keep) {
      int p = atomicAdd(&s_pos[e], 1);
      ids[p] = t;
      wt[p] = w[i];
      slot_tj[i] = p;
    } else {
      slot_tj[i] = -1;
    }
  }
}

// ---- hidden fp32 -> bf16 once ----
__global__ void cvt_hidden(const float* __restrict__ hs, char* __restrict__ ws) {
  int g = blockIdx.x * 256 + threadIdx.x;            // 524288 threads, 8 elem each
  const float4 f0 = ((const float4*)hs)[g * 2];
  const float4 f1 = ((const float4*)hs)[g * 2 + 1];
  uint4 o;
  o.x = pkbf(f0.x, f0.y); o.y = pkbf(f0.z, f0.w);
  o.z = pkbf(f1.x, f1.y); o.w = pkbf(f1.z, f1.w);
  ((uint4*)(ws + WS_HID16))[g] = o;
}

// ===== GEMM1: gathered hid16 [cnt,2048] x gate_up[e][2048,1536], fused silu*up =====
// Double-buffered 2-phase pipeline, one barrier per K-step.
// A: global_load_lds (16B) into linear [128][64] bf16, source pre-swizzled with
//    granule XOR (r&7); read at c16 = (ks*4+quad)^(row&7).
// B: 8x float4 loads (k-pair scheme) issued at iter start, packed-cvt + XOR-swizzled
//    transposed ds_write_b32 AFTER the MFMA phase (latency hidden under compute).
//    Bl [col][72] pitch; chunk (k2>>2)^(c4&7); read ch = (ks*4+quad)^((j>>2)&7).
__global__ __launch_bounds__(256, 2) void gemm1(
    const float* __restrict__ gup, char* __restrict__ ws) {
  const int* offs = (const int*)(ws + WS_OFFSETS);
  const int* ids  = (const int*)(ws + WS_IDS);
  const int* tiles = (const int*)(ws + WS_TILES);
  const unsigned short* h16 = (const unsigned short*)(ws + WS_HID16);
  unsigned short* inter = (unsigned short*)(ws + WS_INTER);

  int tl = tiles[blockIdx.y];
  if (tl < 0) return;
  int e = tl >> 16, m0 = (tl & 0xffff) << 7;
  int start = offs[e];
  int mrem = offs[e + 1] - start - m0;
  int n0 = blockIdx.x * 64;

  __shared__ __align__(16) unsigned short Al[2][128 * 64];   // 32 KB
  __shared__ __align__(16) unsigned short Bl[2][128][72];    // 36.9 KB

  int tid = threadIdx.x, lane = tid & 63, wid = tid >> 6;
  int wy = wid >> 1, wx = wid & 1, quad = lane >> 4, l15 = lane & 15;

  floatx4 acc[4][4] = {};

  // ---- A map: gload_lds slots, pre-swizzled gathered source ----
  const unsigned short* aSrc[4];
#pragma unroll
  for (int u = 0; u < 4; ++u) {
    int s = (wid * 4 + u) * 64 + lane;       // linear 16B slot 0..1023
    int r = s >> 3;
    int c = (s & 7) ^ (r & 7);
    int tok = ids[start + m0 + ((r < mrem) ? r : 0)];
    aSrc[u] = h16 + (size_t)tok * H_ + c * 8;
  }
  // ---- B map: 4 k-pair units/thread ----
  const float* gB[4];
  int brow0[4], bofs[4];
#pragma unroll
  for (int pp = 0; pp < 4; ++pp) {
    int lin2 = tid + 256 * pp;
    int k2 = lin2 >> 5, c4 = lin2 & 31;
    int gcol = (c4 < 16) ? (n0 + c4 * 4) : (I_ + n0 + (c4 - 16) * 4);
    gB[pp] = gup + (size_t)e * H_ * TWO_I + (size_t)(2 * k2) * TWO_I + gcol;
    brow0[pp] = c4 * 4;
    bofs[pp] = (((k2 >> 2) ^ (c4 & 7)) * 8) + (k2 & 3) * 2;
  }

  float4 pf0[4], pf1[4];

  auto loadB = [&](int kb) {
#pragma unroll
    for (int pp = 0; pp < 4; ++pp) {
      const float* p = gB[pp] + (size_t)kb * 64 * TWO_I;
      pf0[pp] = *(const float4*)p;
      pf1[pp] = *(const float4*)(p + TWO_I);
    }
  };
  auto stageA = [&](int kb, int buf) {
#pragma unroll
    for (int u = 0; u < 4; ++u)
      gload_lds16(aSrc[u] + kb * 64, &Al[buf][(wid * 4 + u) * 512]);
  };
  auto writeB = [&](int buf) {
#pragma unroll
    for (int pp = 0; pp < 4; ++pp) {
      *(unsigned*)&Bl[buf][brow0[pp] + 0][bofs[pp]] = pkbf(pf0[pp].x, pf1[pp].x);
      *(unsigned*)&Bl[buf][brow0[pp] + 1][bofs[pp]] = pkbf(pf0[pp].y, pf1[pp].y);
      *(unsigned*)&Bl[buf][brow0[pp] + 2][bofs[pp]] = pkbf(pf0[pp].z, pf1[pp].z);
      *(unsigned*)&Bl[buf][brow0[pp] + 3][bofs[pp]] = pkbf(pf0[pp].w, pf1[pp].w);
    }
  };
  auto compute = [&](int buf) {
#pragma unroll
    for (int ks = 0; ks < 2; ++ks) {
      short8 af[4], bfr[4];
#pragma unroll
      for (int mi = 0; mi < 4; ++mi) {
        int row = wy * 64 + mi * 16 + l15;
        int c16 = (ks * 4 + quad) ^ (row & 7);
        af[mi] = *(const short8*)&Al[buf][row * 64 + c16 * 8];
      }
#pragma unroll
      for (int ni = 0; ni < 4; ++ni) {
        int j = (ni < 2) ? (wx * 32 + ni * 16 + l15) : (64 + wx * 32 + (ni - 2) * 16 + l15);
        int ch = (ks * 4 + quad) ^ ((j >> 2) & 7);
        bfr[ni] = *(const short8*)&Bl[buf][j][ch * 8];
      }
#pragma unroll
      for (int mi = 0; mi < 4; ++mi)
#pragma unroll
        for (int ni = 0; ni < 4; ++ni)
          acc[mi][ni] = __builtin_amdgcn_mfma_f32_16x16x32_bf16(af[mi], bfr[ni], acc[mi][ni], 0, 0, 0);
    }
  };

  const int NK = H_ / 64;   // 32
  // prologue: stage tile 0 into buffer 0
  loadB(0);
  stageA(0, 0);
  writeB(0);               // compiler waits the pf loads (counted vmcnt)
  __syncthreads();         // drains gload_lds -> Al[0] visible

  for (int kb = 0; kb < NK; ++kb) {
    int cur = kb & 1, nxt = cur ^ 1;
    if (kb + 1 < NK) {
      loadB(kb + 1);           // B transit loads first (oldest -> counted wait)
      stageA(kb + 1, nxt);     // A DMA into next buffer
    }
    compute(cur);
    __builtin_amdgcn_sched_barrier(0);   // keep B LDS-writes (and their wait) after MFMAs
    if (kb + 1 < NK) writeB(nxt);
    __syncthreads();           // single barrier per K-step
  }

  // epilogue: inter = silu(gate) * up
#pragma unroll
  for (int mi = 0; mi < 4; ++mi) {
#pragma unroll
    for (int r = 0; r < 4; ++r) {
      int row = wy * 64 + mi * 16 + quad * 4 + r;
      if (row < mrem) {
        int slot = start + m0 + row;
#pragma unroll
        for (int ni = 0; ni < 2; ++ni) {
          float g = acc[mi][ni][r];
          float u = acc[mi][ni + 2][r];
          float s = g / (1.f + __expf(-g));
          int col = n0 + wx * 32 + ni * 16 + l15;
          inter[(size_t)slot * I_ + col] = f2bf(s * u);
        }
      }
    }
  }
}

// ===== GEMM2: inter [cnt,768] x down[e][768,2048]; weighted store to eo (no atomics) =====
__global__ __launch_bounds__(256, 2) void gemm2(
    const float* __restrict__ down, char* __restrict__ ws) {
  const int* offs = (const int*)(ws + WS_OFFSETS);
  const int* ids  = (const int*)(ws + WS_IDS);
  const float* wt = (const float*)(ws + WS_WTS);
  const int* tiles = (const int*)(ws + WS_TILES);
  const unsigned short* inter = (const unsigned short*)(ws + WS_INTER);
  float* eo = (float*)(ws + WS_EO);

  int tl = tiles[blockIdx.y];
  if (tl < 0) return;
  int e = tl >> 16, m0 = (tl & 0xffff) << 7;
  int start = offs[e];
  int mrem = offs[e + 1] - start - m0;
  int n0 = blockIdx.x * 128;

  __shared__ __align__(16) unsigned short Al[2][128 * 64];
  __shared__ __align__(16) unsigned short Bl[2][128][72];

  int tid = threadIdx.x, lane = tid & 63, wid = tid >> 6;
  int wy = wid >> 1, wx = wid & 1, quad = lane >> 4, l15 = lane & 15;

  floatx4 acc[4][4] = {};

  const unsigned short* aSrc[4];
#pragma unroll
  for (int u = 0; u < 4; ++u) {
    int s = (wid * 4 + u) * 64 + lane;
    int r = s >> 3;
    int c = (s & 7) ^ (r & 7);
    int arow = (r < mrem) ? r : 0;
    aSrc[u] = inter + (size_t)(start + m0 + arow) * I_ + c * 8;
  }
  const float* gB[4];
  int brow0[4], bofs[4];
#pragma unroll
  for (int pp = 0; pp < 4; ++pp) {
    int lin2 = tid + 256 * pp;
    int k2 = lin2 >> 5, c4 = lin2 & 31;
    gB[pp] = down + (size_t)e * I_ * H_ + (size_t)(2 * k2) * H_ + (n0 + c4 * 4);
    brow0[pp] = c4 * 4;
    bofs[pp] = (((k2 >> 2) ^ (c4 & 7)) * 8) + (k2 & 3) * 2;
  }

  float4 pf0[4], pf1[4];

  auto loadB = [&](int kb) {
#pragma unroll
    for (int pp = 0; pp < 4; ++pp) {
      const float* p = gB[pp] + (size_t)kb * 64 * H_;
      pf0[pp] = *(const float4*)p;
      pf1[pp] = *(const float4*)(p + H_);
    }
  };
  auto stageA = [&](int kb, int buf) {
#pragma unroll
    for (int u = 0; u < 4; ++u)
      gload_lds16(aSrc[u] + kb * 64, &Al[buf][(wid * 4 + u) * 512]);
  };
  auto writeB = [&](int buf) {
#pragma unroll
    for (int pp = 0; pp < 4; ++pp) {
      *(unsigned*)&Bl[buf][brow0[pp] + 0][bofs[pp]] = pkbf(pf0[pp].x, pf1[pp].x);
      *(unsigned*)&Bl[buf][brow0[pp] + 1][bofs[pp]] = pkbf(pf0[pp].y, pf1[pp].y);
      *(unsigned*)&Bl[buf][brow0[pp] + 2][bofs[pp]] = pkbf(pf0[pp].z, pf1[pp].z);
      *(unsigned*)&Bl[buf][brow0[pp] + 3][bofs[pp]] = pkbf(pf0[pp].w, pf1[pp].w);
    }
  };
  auto compute = [&](int buf) {
#pragma unroll
    for (int ks = 0; ks < 2; ++ks) {
      short8 af[4], bfr[4];
#pragma unroll
      for (int mi = 0; mi < 4; ++mi) {
        int row = wy * 64 + mi * 16 + l15;
        int c16 = (ks * 4 + quad) ^ (row & 7);
        af[mi] = *(const short8*)&Al[buf][row * 64 + c16 * 8];
      }
#pragma unroll
      for (int ni = 0; ni < 4; ++ni) {
        int j = wx * 64 + ni * 16 + l15;
        int ch = (ks * 4 + quad) ^ ((j >> 2) & 7);
        bfr[ni] = *(const short8*)&Bl[buf][j][ch * 8];
      }
#pragma unroll
      for (int mi = 0; mi < 4; ++mi)
#pragma unroll
        for (int ni = 0; ni < 4; ++ni)
          acc[mi][ni] = __builtin_amdgcn_mfma_f32_16x16x32_bf16(af[mi], bfr[ni], acc[mi][ni], 0, 0, 0);
    }
  };

  const int NK = I_ / 64;   // 12
  loadB(0);
  stageA(0, 0);
  writeB(0);
  __syncthreads();

  for (int kb = 0; kb < NK; ++kb) {
    int cur = kb & 1, nxt = cur ^ 1;
    if (kb + 1 < NK) {
      loadB(kb + 1);
      stageA(kb + 1, nxt);
    }
    compute(cur);
    __builtin_amdgcn_sched_barrier(0);
    if (kb + 1 < NK) writeB(nxt);
    __syncthreads();
  }

#pragma unroll
  for (int mi = 0; mi < 4; ++mi) {
#pragma unroll
    for (int r = 0; r < 4; ++r) {
      int row = wy * 64 + mi * 16 + quad * 4 + r;
      if (row < mrem) {
        int slot = start + m0 + row;
        float wv = wt[slot];
#pragma unroll
        for (int ni = 0; ni < 4; ++ni) {
          int col = n0 + wx * 64 + ni * 16 + l15;
          eo[(size_t)slot * H_ + col] = wv * acc[mi][ni][r];
        }
      }
    }
  }
}

// ---- combine: out[t] = sum over valid slots of eo[slot] (weights folded in gemm2) ----
__global__ void combine(float* __restrict__ out, const char* __restrict__ ws) {
  const int* slot_tj = (const int*)(ws + WS_SLOTTJ);
  const float* eo = (const float*)(ws + WS_EO);
  int g = blockIdx.x * 256 + threadIdx.x;     // T*H/4 = 1048576 threads
  int token = g >> 9, c4 = g & 511;
  const int* st = slot_tj + token * 4;
  float4 s = {0.f, 0.f, 0.f, 0.f};
#pragma unroll
  for (int j = 0; j < 4; ++j) {
    int p = st[j];
    if (p >= 0) {
      const float4 v = *(const float4*)(eo + (size_t)p * H_ + c4 * 4);
      s.x += v.x; s.y += v.y; s.z += v.z; s.w += v.w;
    }
  }
  *(float4*)(out + (size_t)token * H_ + c4 * 4) = s;
}

extern "C" void kernel_launch(void* const* d_in, const int* in_sizes, int n_in,
                              void* d_out, int out_size, void* d_ws, size_t ws_size,
                              hipStream_t stream) {
  (void)in_sizes; (void)n_in; (void)out_size; (void)ws_size;
  const float* hidden = (const float*)d_in[0];
  const int* idx      = (const int*)d_in[1];
  const float* w      = (const float*)d_in[2];
  const float* gup    = (const float*)d_in[3];
  const float* down   = (const float*)d_in[4];
  float* out = (float*)d_out;
  char* ws = (char*)d_ws;

  build_routing<<<1, 256, 0, stream>>>(idx, w, ws);
  cvt_hidden<<<T_ * H_ / 8 / 256, 256, 0, stream>>>(hidden, ws);
  gemm1<<<dim3(I_ / 64, MAX_TILES), 256, 0, stream>>>(gup, ws);
  gemm2<<<dim3(H_ / 128, MAX_TILES), 256, 0, stream>>>(down, ws);
  combine<<<T_ * H_ / 4 / 256, 256, 0, stream>>>(out, ws);
}

// Round 4
// 819.103 us; speedup vs baseline: 1.0153x; 1.0153x over previous
//
#include <hip/hip_runtime.h>
#include <hip/hip_bf16.h>

// Qwen3VLMoeTextExpertsTransposed: E=32,H=2048,I=768,K=4,T=2048
#define E_ 32
#define H_ 2048
#define I_ 768
#define T_ 2048
#define TWO_I 1536
#define MAX_TILES 96   // sum ceil(cnt/128) <= 32 + 8192/128 = 96

typedef __attribute__((ext_vector_type(8))) short short8;
typedef __attribute__((ext_vector_type(4))) float floatx4;

// ws layout (bytes)
#define WS_OFFSETS 0                       // int[33]
#define WS_IDS     1024                    // int[8192]
#define WS_WTS     (1024 + 32768)          // float[8192]
#define WS_TILES   (1024 + 65536)          // int[96]: (e<<16)|mtile, -1 = dead
#define WS_SLOTTJ  69632                   // int[8192]: slot of (t,j) or -1
#define WS_INTER   131072                  // bf16[8192*768]
#define WS_HID16   (131072 + 8192*768*2)   // bf16[2048*2048]
#define WS_EO      21102592ULL             // fp32[8192*2048] weighted expert outs (67 MB)

__device__ __forceinline__ unsigned short f2bf(float f) {
  union { float f; unsigned u; } v; v.f = f;
  unsigned r = v.u + 0x7FFFu + ((v.u >> 16) & 1u);   // RNE
  return (unsigned short)(r >> 16);
}

__device__ __forceinline__ unsigned pkbf(float a, float b) {
  // packed fp32->bf16 RNE pair; lowers to v_cvt_pk_bf16_f32 when available
  __hip_bfloat162 h = __float22bfloat162_rn(float2{a, b});
  union { __hip_bfloat162 h; unsigned u; } v; v.h = h; return v.u;
}

// async global->LDS, 16B per lane; LDS dest = wave-uniform base + lane*16
__device__ __forceinline__ void gload_lds16(const unsigned short* g, unsigned short* l) {
  __builtin_amdgcn_global_load_lds(
      (__attribute__((address_space(1))) void*)g,
      (__attribute__((address_space(3))) void*)l, 16, 0, 0);
}

// ---- routing: group slots by expert (dedupe = numpy last-write-wins) + tile list ----
__global__ void build_routing(const int* __restrict__ idx, const float* __restrict__ w,
                              char* __restrict__ ws) {
  int* offs = (int*)(ws + WS_OFFSETS);
  int* ids  = (int*)(ws + WS_IDS);
  float* wt = (float*)(ws + WS_WTS);
  int* tiles = (int*)(ws + WS_TILES);
  int* slot_tj = (int*)(ws + WS_SLOTTJ);
  __shared__ int s_cnt[E_];
  __shared__ int s_pos[E_];
  int tid = threadIdx.x;
  if (tid < E_) s_cnt[tid] = 0;
  __syncthreads();
  for (int i = tid; i < T_ * 4; i += 256) {
    int t = i >> 2, j = i & 3;
    int e = idx[i];
    bool keep = true;
    for (int j2 = j + 1; j2 < 4; ++j2) if (idx[t * 4 + j2] == e) keep = false;
    if (keep) atomicAdd(&s_cnt[e], 1);
  }
  __syncthreads();
  if (tid == 0) {
    int run = 0;
    for (int e = 0; e < E_; ++e) { offs[e] = run; s_pos[e] = run; run += s_cnt[e]; }
    offs[E_] = run;
    int nt = 0;
    for (int e = 0; e < E_; ++e)
      for (int m0 = 0; m0 < s_cnt[e]; m0 += 128) tiles[nt++] = (e << 16) | (m0 >> 7);
    for (; nt < MAX_TILES; ++nt) tiles[nt] = -1;
  }
  __syncthreads();
  for (int i = tid; i < T_ * 4; i += 256) {
    int t = i >> 2, j = i & 3;
    int e = idx[i];
    bool keep = true;
    for (int j2 = j + 1; j2 < 4; ++j2) if (idx[t * 4 + j2] == e) keep = false;
    if (keep) {
      int p = atomicAdd(&s_pos[e], 1);
      ids[p] = t;
      wt[p] = w[i];
      slot_tj[i] = p;
    } else {
      slot_tj[i] = -1;
    }
  }
}

// ---- hidden fp32 -> bf16 once ----
__global__ void cvt_hidden(const float* __restrict__ hs, char* __restrict__ ws) {
  int g = blockIdx.x * 256 + threadIdx.x;            // 524288 threads, 8 elem each
  const float4 f0 = ((const float4*)hs)[g * 2];
  const float4 f1 = ((const float4*)hs)[g * 2 + 1];
  uint4 o;
  o.x = pkbf(f0.x, f0.y); o.y = pkbf(f0.z, f0.w);
  o.z = pkbf(f1.x, f1.y); o.w = pkbf(f1.z, f1.w);
  ((uint4*)(ws + WS_HID16))[g] = o;
}

// ===== GEMM1: gathered hid16 [cnt,2048] x gate_up[e][2048,1536], fused silu*up =====
// Double-buffered, TWO raw barriers per K-step, COUNTED vmcnt (no full drain).
// Steady state: issue loadB(k+1)+stageA(k+1) -> vmcnt(12) (waits only prev A-DMAs)
// -> barrier -> MFMA(cur) -> barrier -> writeB(k+1) (auto vmcnt(4) for reg deps).
__global__ __launch_bounds__(256, 2) void gemm1(
    const float* __restrict__ gup, char* __restrict__ ws) {
  const int* offs = (const int*)(ws + WS_OFFSETS);
  const int* ids  = (const int*)(ws + WS_IDS);
  const int* tiles = (const int*)(ws + WS_TILES);
  const unsigned short* h16 = (const unsigned short*)(ws + WS_HID16);
  unsigned short* inter = (unsigned short*)(ws + WS_INTER);

  int tl = tiles[blockIdx.y];
  if (tl < 0) return;
  int e = tl >> 16, m0 = (tl & 0xffff) << 7;
  int start = offs[e];
  int mrem = offs[e + 1] - start - m0;
  int n0 = blockIdx.x * 64;

  __shared__ __align__(16) unsigned short Al[2][128 * 64];   // 32 KB
  __shared__ __align__(16) unsigned short Bl[2][128][72];    // 36.9 KB

  int tid = threadIdx.x, lane = tid & 63, wid = tid >> 6;
  int wy = wid >> 1, wx = wid & 1, quad = lane >> 4, l15 = lane & 15;

  floatx4 acc[4][4] = {};

  // ---- A map: gload_lds slots, pre-swizzled gathered source ----
  const unsigned short* aSrc[4];
#pragma unroll
  for (int u = 0; u < 4; ++u) {
    int s = (wid * 4 + u) * 64 + lane;       // linear 16B slot 0..1023
    int r = s >> 3;
    int c = (s & 7) ^ (r & 7);
    int tok = ids[start + m0 + ((r < mrem) ? r : 0)];
    aSrc[u] = h16 + (size_t)tok * H_ + c * 8;
  }
  // ---- B map: 4 k-pair units/thread ----
  const float* gB[4];
  int brow0[4], bofs[4];
#pragma unroll
  for (int pp = 0; pp < 4; ++pp) {
    int lin2 = tid + 256 * pp;
    int k2 = lin2 >> 5, c4 = lin2 & 31;
    int gcol = (c4 < 16) ? (n0 + c4 * 4) : (I_ + n0 + (c4 - 16) * 4);
    gB[pp] = gup + (size_t)e * H_ * TWO_I + (size_t)(2 * k2) * TWO_I + gcol;
    brow0[pp] = c4 * 4;
    bofs[pp] = (((k2 >> 2) ^ (c4 & 7)) * 8) + (k2 & 3) * 2;
  }

  float4 pf0[4], pf1[4];

  auto loadB = [&](int kb) {
#pragma unroll
    for (int pp = 0; pp < 4; ++pp) {
      const float* p = gB[pp] + (size_t)kb * 64 * TWO_I;
      pf0[pp] = *(const float4*)p;
      pf1[pp] = *(const float4*)(p + TWO_I);
    }
  };
  auto stageA = [&](int kb, int buf) {
#pragma unroll
    for (int u = 0; u < 4; ++u)
      gload_lds16(aSrc[u] + kb * 64, &Al[buf][(wid * 4 + u) * 512]);
  };
  auto writeB = [&](int buf) {
#pragma unroll
    for (int pp = 0; pp < 4; ++pp) {
      *(unsigned*)&Bl[buf][brow0[pp] + 0][bofs[pp]] = pkbf(pf0[pp].x, pf1[pp].x);
      *(unsigned*)&Bl[buf][brow0[pp] + 1][bofs[pp]] = pkbf(pf0[pp].y, pf1[pp].y);
      *(unsigned*)&Bl[buf][brow0[pp] + 2][bofs[pp]] = pkbf(pf0[pp].z, pf1[pp].z);
      *(unsigned*)&Bl[buf][brow0[pp] + 3][bofs[pp]] = pkbf(pf0[pp].w, pf1[pp].w);
    }
  };
  auto compute = [&](int buf) {
#pragma unroll
    for (int ks = 0; ks < 2; ++ks) {
      short8 af[4], bfr[4];
#pragma unroll
      for (int mi = 0; mi < 4; ++mi) {
        int row = wy * 64 + mi * 16 + l15;
        int c16 = (ks * 4 + quad) ^ (row & 7);
        af[mi] = *(const short8*)&Al[buf][row * 64 + c16 * 8];
      }
#pragma unroll
      for (int ni = 0; ni < 4; ++ni) {
        int j = (ni < 2) ? (wx * 32 + ni * 16 + l15) : (64 + wx * 32 + (ni - 2) * 16 + l15);
        int ch = (ks * 4 + quad) ^ ((j >> 2) & 7);
        bfr[ni] = *(const short8*)&Bl[buf][j][ch * 8];
      }
#pragma unroll
      for (int mi = 0; mi < 4; ++mi)
#pragma unroll
        for (int ni = 0; ni < 4; ++ni)
          acc[mi][ni] = __builtin_amdgcn_mfma_f32_16x16x32_bf16(af[mi], bfr[ni], acc[mi][ni], 0, 0, 0);
    }
  };

  const int NK = H_ / 64;   // 32
  // prologue: stage tile 0 into buffer 0 (full drain once)
  loadB(0);
  stageA(0, 0);
  writeB(0);                       // compiler waits the 8 B loads (vmcnt(4))
  asm volatile("s_waitcnt vmcnt(0) lgkmcnt(0)" ::: "memory");
  __builtin_amdgcn_sched_barrier(0);
  __builtin_amdgcn_s_barrier();
  __builtin_amdgcn_sched_barrier(0);

  for (int kb = 0; kb < NK - 1; ++kb) {
    int cur = kb & 1, nxt = cur ^ 1;
    loadB(kb + 1);                 // 8 vmem -> regs (stay in flight)
    stageA(kb + 1, nxt);           // 4 DMA -> Al[nxt] (stay in flight)
    // wait ONLY prev tile's 4 A-DMAs (oldest); 12 just-issued remain outstanding
    asm volatile("s_waitcnt vmcnt(12) lgkmcnt(0)" ::: "memory");
    __builtin_amdgcn_sched_barrier(0);
    __builtin_amdgcn_s_barrier();          // all waves: cur fully staged
    __builtin_amdgcn_sched_barrier(0);
    compute(cur);
    __builtin_amdgcn_sched_barrier(0);
    __builtin_amdgcn_s_barrier();          // all waves done READING cur/nxt
    __builtin_amdgcn_sched_barrier(0);
    writeB(nxt);                   // auto vmcnt(4) for pf reg deps
  }
  // epilogue tile
  {
    int cur = (NK - 1) & 1;
    asm volatile("s_waitcnt vmcnt(0) lgkmcnt(0)" ::: "memory");
    __builtin_amdgcn_sched_barrier(0);
    __builtin_amdgcn_s_barrier();
    __builtin_amdgcn_sched_barrier(0);
    compute(cur);
  }

  // epilogue: inter = silu(gate) * up
#pragma unroll
  for (int mi = 0; mi < 4; ++mi) {
#pragma unroll
    for (int r = 0; r < 4; ++r) {
      int row = wy * 64 + mi * 16 + quad * 4 + r;
      if (row < mrem) {
        int slot = start + m0 + row;
#pragma unroll
        for (int ni = 0; ni < 2; ++ni) {
          float g = acc[mi][ni][r];
          float u = acc[mi][ni + 2][r];
          float s = g / (1.f + __expf(-g));
          int col = n0 + wx * 32 + ni * 16 + l15;
          inter[(size_t)slot * I_ + col] = f2bf(s * u);
        }
      }
    }
  }
}

// ===== GEMM2: inter [cnt,768] x down[e][768,2048]; weighted store to eo (no atomics) =====
__global__ __launch_bounds__(256, 2) void gemm2(
    const float* __restrict__ down, char* __restrict__ ws) {
  const int* offs = (const int*)(ws + WS_OFFSETS);
  const int* ids  = (const int*)(ws + WS_IDS);
  const float* wt = (const float*)(ws + WS_WTS);
  const int* tiles = (const int*)(ws + WS_TILES);
  const unsigned short* inter = (const unsigned short*)(ws + WS_INTER);
  float* eo = (float*)(ws + WS_EO);

  int tl = tiles[blockIdx.y];
  if (tl < 0) return;
  int e = tl >> 16, m0 = (tl & 0xffff) << 7;
  int start = offs[e];
  int mrem = offs[e + 1] - start - m0;
  int n0 = blockIdx.x * 128;

  __shared__ __align__(16) unsigned short Al[2][128 * 64];
  __shared__ __align__(16) unsigned short Bl[2][128][72];

  int tid = threadIdx.x, lane = tid & 63, wid = tid >> 6;
  int wy = wid >> 1, wx = wid & 1, quad = lane >> 4, l15 = lane & 15;

  floatx4 acc[4][4] = {};

  const unsigned short* aSrc[4];
#pragma unroll
  for (int u = 0; u < 4; ++u) {
    int s = (wid * 4 + u) * 64 + lane;
    int r = s >> 3;
    int c = (s & 7) ^ (r & 7);
    int arow = (r < mrem) ? r : 0;
    aSrc[u] = inter + (size_t)(start + m0 + arow) * I_ + c * 8;
  }
  const float* gB[4];
  int brow0[4], bofs[4];
#pragma unroll
  for (int pp = 0; pp < 4; ++pp) {
    int lin2 = tid + 256 * pp;
    int k2 = lin2 >> 5, c4 = lin2 & 31;
    gB[pp] = down + (size_t)e * I_ * H_ + (size_t)(2 * k2) * H_ + (n0 + c4 * 4);
    brow0[pp] = c4 * 4;
    bofs[pp] = (((k2 >> 2) ^ (c4 & 7)) * 8) + (k2 & 3) * 2;
  }

  float4 pf0[4], pf1[4];

  auto loadB = [&](int kb) {
#pragma unroll
    for (int pp = 0; pp < 4; ++pp) {
      const float* p = gB[pp] + (size_t)kb * 64 * H_;
      pf0[pp] = *(const float4*)p;
      pf1[pp] = *(const float4*)(p + H_);
    }
  };
  auto stageA = [&](int kb, int buf) {
#pragma unroll
    for (int u = 0; u < 4; ++u)
      gload_lds16(aSrc[u] + kb * 64, &Al[buf][(wid * 4 + u) * 512]);
  };
  auto writeB = [&](int buf) {
#pragma unroll
    for (int pp = 0; pp < 4; ++pp) {
      *(unsigned*)&Bl[buf][brow0[pp] + 0][bofs[pp]] = pkbf(pf0[pp].x, pf1[pp].x);
      *(unsigned*)&Bl[buf][brow0[pp] + 1][bofs[pp]] = pkbf(pf0[pp].y, pf1[pp].y);
      *(unsigned*)&Bl[buf][brow0[pp] + 2][bofs[pp]] = pkbf(pf0[pp].z, pf1[pp].z);
      *(unsigned*)&Bl[buf][brow0[pp] + 3][bofs[pp]] = pkbf(pf0[pp].w, pf1[pp].w);
    }
  };
  auto compute = [&](int buf) {
#pragma unroll
    for (int ks = 0; ks < 2; ++ks) {
      short8 af[4], bfr[4];
#pragma unroll
      for (int mi = 0; mi < 4; ++mi) {
        int row = wy * 64 + mi * 16 + l15;
        int c16 = (ks * 4 + quad) ^ (row & 7);
        af[mi] = *(const short8*)&Al[buf][row * 64 + c16 * 8];
      }
#pragma unroll
      for (int ni = 0; ni < 4; ++ni) {
        int j = wx * 64 + ni * 16 + l15;
        int ch = (ks * 4 + quad) ^ ((j >> 2) & 7);
        bfr[ni] = *(const short8*)&Bl[buf][j][ch * 8];
      }
#pragma unroll
      for (int mi = 0; mi < 4; ++mi)
#pragma unroll
        for (int ni = 0; ni < 4; ++ni)
          acc[mi][ni] = __builtin_amdgcn_mfma_f32_16x16x32_bf16(af[mi], bfr[ni], acc[mi][ni], 0, 0, 0);
    }
  };

  const int NK = I_ / 64;   // 12
  loadB(0);
  stageA(0, 0);
  writeB(0);
  asm volatile("s_waitcnt vmcnt(0) lgkmcnt(0)" ::: "memory");
  __builtin_amdgcn_sched_barrier(0);
  __builtin_amdgcn_s_barrier();
  __builtin_amdgcn_sched_barrier(0);

  for (int kb = 0; kb < NK - 1; ++kb) {
    int cur = kb & 1, nxt = cur ^ 1;
    loadB(kb + 1);
    stageA(kb + 1, nxt);
    asm volatile("s_waitcnt vmcnt(12) lgkmcnt(0)" ::: "memory");
    __builtin_amdgcn_sched_barrier(0);
    __builtin_amdgcn_s_barrier();
    __builtin_amdgcn_sched_barrier(0);
    compute(cur);
    __builtin_amdgcn_sched_barrier(0);
    __builtin_amdgcn_s_barrier();
    __builtin_amdgcn_sched_barrier(0);
    writeB(nxt);
  }
  {
    int cur = (NK - 1) & 1;
    asm volatile("s_waitcnt vmcnt(0) lgkmcnt(0)" ::: "memory");
    __builtin_amdgcn_sched_barrier(0);
    __builtin_amdgcn_s_barrier();
    __builtin_amdgcn_sched_barrier(0);
    compute(cur);
  }

#pragma unroll
  for (int mi = 0; mi < 4; ++mi) {
#pragma unroll
    for (int r = 0; r < 4; ++r) {
      int row = wy * 64 + mi * 16 + quad * 4 + r;
      if (row < mrem) {
        int slot = start + m0 + row;
        float wv = wt[slot];
#pragma unroll
        for (int ni = 0; ni < 4; ++ni) {
          int col = n0 + wx * 64 + ni * 16 + l15;
          eo[(size_t)slot * H_ + col] = wv * acc[mi][ni][r];
        }
      }
    }
  }
}

// ---- combine: out[t] = sum over valid slots of eo[slot] (weights folded in gemm2) ----
__global__ void combine(float* __restrict__ out, const char* __restrict__ ws) {
  const int* slot_tj = (const int*)(ws + WS_SLOTTJ);
  const float* eo = (const float*)(ws + WS_EO);
  int g = blockIdx.x * 256 + threadIdx.x;     // T*H/4 = 1048576 threads
  int token = g >> 9, c4 = g & 511;
  const int* st = slot_tj + token * 4;
  float4 s = {0.f, 0.f, 0.f, 0.f};
#pragma unroll
  for (int j = 0; j < 4; ++j) {
    int p = st[j];
    if (p >= 0) {
      const float4 v = *(const float4*)(eo + (size_t)p * H_ + c4 * 4);
      s.x += v.x; s.y += v.y; s.z += v.z; s.w += v.w;
    }
  }
  *(float4*)(out + (size_t)token * H_ + c4 * 4) = s;
}

extern "C" void kernel_launch(void* const* d_in, const int* in_sizes, int n_in,
                              void* d_out, int out_size, void* d_ws, size_t ws_size,
                              hipStream_t stream) {
  (void)in_sizes; (void)n_in; (void)out_size; (void)ws_size;
  const float* hidden = (const float*)d_in[0];
  const int* idx      = (const int*)d_in[1];
  const float* w      = (const float*)d_in[2];
  const float* gup    = (const float*)d_in[3];
  const float* down   = (const float*)d_in[4];
  float* out = (float*)d_out;
  char* ws = (char*)d_ws;

  build_routing<<<1, 256, 0, stream>>>(idx, w, ws);
  cvt_hidden<<<T_ * H_ / 8 / 256, 256, 0, stream>>>(hidden, ws);
  gemm1<<<dim3(I_ / 64, MAX_TILES), 256, 0, stream>>>(gup, ws);
  gemm2<<<dim3(H_ / 128, MAX_TILES), 256, 0, stream>>>(down, ws);
  combine<<<T_ * H_ / 4 / 256, 256, 0, stream>>>(out, ws);
}